// Round 10
// baseline (567.378 us; speedup 1.0000x reference)
//
#include <hip/hip_runtime.h>

#define LN_EPS 1e-5f

typedef unsigned short ushortT;

__device__ __forceinline__ float4 ld4(const float* p) { return *reinterpret_cast<const float4*>(p); }
__device__ __forceinline__ void st4(float* p, float4 v) { *reinterpret_cast<float4*>(p) = v; }
__device__ __forceinline__ float bf2f(unsigned u) { return __uint_as_float(u << 16); }
__device__ __forceinline__ unsigned short f2bf(float f) {
    unsigned u = __float_as_uint(f);
    u += 0x7fffu + ((u >> 16) & 1u);   // round to nearest even
    return (unsigned short)(u >> 16);
}
__device__ __forceinline__ unsigned pack2(float a, float b) {
    return (unsigned)f2bf(a) | ((unsigned)f2bf(b) << 16);
}

// accumulate 8 bf16 lanes (packed in uint4) scaled by wt into a[8]
__device__ __forceinline__ void acc8(float (&a)[8], uint4 v, float wt) {
    a[0] = fmaf(bf2f(v.x & 0xffffu), wt, a[0]); a[1] = fmaf(bf2f(v.x >> 16), wt, a[1]);
    a[2] = fmaf(bf2f(v.y & 0xffffu), wt, a[2]); a[3] = fmaf(bf2f(v.y >> 16), wt, a[3]);
    a[4] = fmaf(bf2f(v.z & 0xffffu), wt, a[4]); a[5] = fmaf(bf2f(v.z >> 16), wt, a[5]);
    a[6] = fmaf(bf2f(v.w & 0xffffu), wt, a[6]); a[7] = fmaf(bf2f(v.w >> 16), wt, a[7]);
}

// ---------------- CSR build ----------------

__global__ __launch_bounds__(256) void k_zero_i32(int* __restrict__ p, int n) {
    int i = blockIdx.x * 256 + threadIdx.x;
    if (i < n) p[i] = 0;
}

__global__ __launch_bounds__(256) void k_count(const int* __restrict__ dst, int* __restrict__ counts, int E) {
    int i = blockIdx.x * 256 + threadIdx.x;
    if (i < E) atomicAdd(&counts[dst[i]], 1);
}

__global__ __launch_bounds__(256) void k_dinv(const int* __restrict__ counts, float* __restrict__ dinv, int n) {
    int i = blockIdx.x * 256 + threadIdx.x;
    if (i < n) dinv[i] = rsqrtf((float)(counts[i] + 1));   // +1 = self loop
}

__global__ __launch_bounds__(512) void k_scan1(const int* __restrict__ counts, int* __restrict__ bsum, int n) {
    __shared__ int s[512];
    int idx = blockIdx.x * 512 + threadIdx.x;
    s[threadIdx.x] = (idx < n) ? counts[idx] : 0;
    __syncthreads();
    for (int d = 256; d > 0; d >>= 1) {
        if (threadIdx.x < d) s[threadIdx.x] += s[threadIdx.x + d];
        __syncthreads();
    }
    if (threadIdx.x == 0) bsum[blockIdx.x] = s[0];
}

__global__ __launch_bounds__(512) void k_scan2(int* __restrict__ bsum, int nb) {
    __shared__ int s[512];
    int t = threadIdx.x;
    int v = (t < nb) ? bsum[t] : 0;
    s[t] = v;
    __syncthreads();
    for (int d = 1; d < 512; d <<= 1) {
        int tv = (t >= d) ? s[t - d] : 0;
        __syncthreads();
        s[t] += tv;
        __syncthreads();
    }
    if (t < nb) bsum[t] = s[t] - v;   // exclusive
}

__global__ __launch_bounds__(512) void k_scan3(const int* __restrict__ counts, const int* __restrict__ bsum,
                                               int* __restrict__ offsets, int* __restrict__ cursor, int n) {
    __shared__ int s[512];
    int tid = threadIdx.x;
    int idx = blockIdx.x * 512 + tid;
    int v = (idx < n) ? counts[idx] : 0;
    s[tid] = v;
    __syncthreads();
    for (int d = 1; d < 512; d <<= 1) {
        int t = (tid >= d) ? s[tid - d] : 0;
        __syncthreads();
        s[tid] += t;
        __syncthreads();
    }
    if (idx < n) {
        int ex = s[tid] - v + bsum[blockIdx.x];
        offsets[idx] = ex;
        cursor[idx] = ex;
    }
}

// src-only CSR fill: one 4B scattered store per edge
__global__ __launch_bounds__(256) void k_fill(const int* __restrict__ src, const int* __restrict__ dst,
                                              int* __restrict__ cursor, int* __restrict__ csr, int E) {
    int i = blockIdx.x * 256 + threadIdx.x;
    if (i < E) {
        int d = dst[i];
        int p = atomicAdd(&cursor[d], 1);
        csr[p] = src[i];
    }
}

// ---------------- f32 -> bf16 convert ----------------

__global__ __launch_bounds__(256) void k_cvt_bf16(const float* __restrict__ in, ushortT* __restrict__ o, int n4) {
    int i = blockIdx.x * 256 + threadIdx.x;
    if (i < n4) {
        float4 v = ld4(in + (size_t)i * 4);
        uint2 pk;
        pk.x = pack2(v.x, v.y);
        pk.y = pack2(v.z, v.w);
        *reinterpret_cast<uint2*>(o + (size_t)i * 4) = pk;
    }
}

// ---------------- L1 fused: Agg(x16) -> @W1 -> +b1/LN/ReLU -> + (x@Ws1+bs1) ----------------
// 512 thr, 64 nodes/block, G=8 lanes/node. LDS ~36KB -> 4 blocks/CU.

__global__ __launch_bounds__(512, 8) void k_l1_fused(
        const ushortT* __restrict__ x16, const int* __restrict__ csr,
        const int* __restrict__ rs, const int* __restrict__ re,
        const float* __restrict__ dinv,
        const float* __restrict__ W1, const float* __restrict__ b1,
        const float* __restrict__ g1, const float* __restrict__ be1,
        const float* __restrict__ Ws1, const float* __restrict__ bs1,
        float* __restrict__ X1, ushortT* __restrict__ X1_16, int n) {
    constexpr int NODES = 64, G = 8, KP = 72;
    __shared__ float Xl[NODES][KP];      // aggregated (f32)
    __shared__ ushortT Xown[NODES][KP];  // own x row (bf16)
    __shared__ float Wl[16][128];

    const int tid = threadIdx.x;

    // ---- Phase A ----
    {
        const int grp = tid / G, sub = tid % G;
        const int node = blockIdx.x * NODES + grp;
        float a[8];
#pragma unroll
        for (int i = 0; i < 8; ++i) a[i] = 0.f;
        uint4 own = make_uint4(0u, 0u, 0u, 0u);

        if (node < n) {
            const float di = dinv[node];
            const ushortT* base = x16 + sub * 8;
            const int p0 = rs[node], p1 = re[node];
            int p = p0;
            for (; p + 4 <= p1; p += 4) {
                int s0 = csr[p], s1 = csr[p + 1], s2 = csr[p + 2], s3 = csr[p + 3];
                float w0 = dinv[s0] * di, w1 = dinv[s1] * di, w2 = dinv[s2] * di, w3 = dinv[s3] * di;
                uint4 v0 = *reinterpret_cast<const uint4*>(base + (size_t)s0 * 64);
                uint4 v1 = *reinterpret_cast<const uint4*>(base + (size_t)s1 * 64);
                uint4 v2 = *reinterpret_cast<const uint4*>(base + (size_t)s2 * 64);
                uint4 v3 = *reinterpret_cast<const uint4*>(base + (size_t)s3 * 64);
                acc8(a, v0, w0); acc8(a, v1, w1); acc8(a, v2, w2); acc8(a, v3, w3);
            }
            for (; p < p1; ++p) {
                int s0 = csr[p];
                float w0 = dinv[s0] * di;
                uint4 v0 = *reinterpret_cast<const uint4*>(base + (size_t)s0 * 64);
                acc8(a, v0, w0);
            }
            own = *reinterpret_cast<const uint4*>(base + (size_t)node * 64);
            acc8(a, own, di * di);
        }
        st4(&Xl[grp][sub * 8], make_float4(a[0], a[1], a[2], a[3]));
        st4(&Xl[grp][sub * 8 + 4], make_float4(a[4], a[5], a[6], a[7]));
        *reinterpret_cast<uint4*>(&Xown[grp][sub * 8]) = own;
    }

    // ---- Phase B1: agg @ W1 (+b1) ----
    const int cg = tid & 31;
    const int rg = tid >> 5;   // 0..15, rows rg*4..rg*4+3
    const float4 b1_4 = ld4(b1 + cg * 4);
    float4 acc[4];
#pragma unroll
    for (int r = 0; r < 4; ++r) acc[r] = b1_4;

    for (int kh = 0; kh < 64; kh += 16) {
        __syncthreads();   // Xl ready (1st) / Wl reuse
        {
            int kk = tid >> 5, c = tid & 31;
            st4(&Wl[kk][c * 4], ld4(W1 + (size_t)(kh + kk) * 128 + c * 4));
        }
        __syncthreads();
#pragma unroll 4
        for (int kk = 0; kk < 16; ++kk) {
            float4 w4 = ld4(&Wl[kk][cg * 4]);
#pragma unroll
            for (int r = 0; r < 4; ++r) {
                float xv = Xl[rg * 4 + r][kh + kk];
                acc[r].x = fmaf(xv, w4.x, acc[r].x);
                acc[r].y = fmaf(xv, w4.y, acc[r].y);
                acc[r].z = fmaf(xv, w4.z, acc[r].z);
                acc[r].w = fmaf(xv, w4.w, acc[r].w);
            }
        }
    }

    // ---- LN + ReLU (into acc) ----
    const float4 g4 = ld4(g1 + cg * 4);
    const float4 be4 = ld4(be1 + cg * 4);
#pragma unroll
    for (int r = 0; r < 4; ++r) {
        float4 a = acc[r];
        float sum = a.x + a.y + a.z + a.w;
#pragma unroll
        for (int m = 16; m > 0; m >>= 1) sum += __shfl_xor(sum, m, 32);
        const float mean = sum * (1.f / 128.f);
        float dx = a.x - mean, dy = a.y - mean, dz = a.z - mean, dw = a.w - mean;
        float sq = dx * dx + dy * dy + dz * dz + dw * dw;
#pragma unroll
        for (int m = 16; m > 0; m >>= 1) sq += __shfl_xor(sq, m, 32);
        const float rstd = rsqrtf(sq * (1.f / 128.f) + LN_EPS);
        acc[r].x = fmaxf(fmaf(dx * rstd, g4.x, be4.x), 0.f);
        acc[r].y = fmaxf(fmaf(dy * rstd, g4.y, be4.y), 0.f);
        acc[r].z = fmaxf(fmaf(dz * rstd, g4.z, be4.z), 0.f);
        acc[r].w = fmaxf(fmaf(dw * rstd, g4.w, be4.w), 0.f);
    }

    // ---- Phase B2: + Xown @ Ws1 ----
    for (int kh = 0; kh < 64; kh += 16) {
        __syncthreads();
        {
            int kk = tid >> 5, c = tid & 31;
            st4(&Wl[kk][c * 4], ld4(Ws1 + (size_t)(kh + kk) * 128 + c * 4));
        }
        __syncthreads();
#pragma unroll 4
        for (int kk = 0; kk < 16; kk += 2) {
            float4 wa = ld4(&Wl[kk][cg * 4]);
            float4 wb = ld4(&Wl[kk + 1][cg * 4]);
#pragma unroll
            for (int r = 0; r < 4; ++r) {
                unsigned xp = *reinterpret_cast<const unsigned*>(&Xown[rg * 4 + r][kh + kk]);
                float x0 = bf2f(xp & 0xffffu), x1 = bf2f(xp >> 16);
                acc[r].x = fmaf(x0, wa.x, acc[r].x); acc[r].y = fmaf(x0, wa.y, acc[r].y);
                acc[r].z = fmaf(x0, wa.z, acc[r].z); acc[r].w = fmaf(x0, wa.w, acc[r].w);
                acc[r].x = fmaf(x1, wb.x, acc[r].x); acc[r].y = fmaf(x1, wb.y, acc[r].y);
                acc[r].z = fmaf(x1, wb.z, acc[r].z); acc[r].w = fmaf(x1, wb.w, acc[r].w);
            }
        }
    }

    const float4 bs4 = ld4(bs1 + cg * 4);
#pragma unroll
    for (int r = 0; r < 4; ++r) {
        int gr = blockIdx.x * NODES + rg * 4 + r;
        if (gr >= n) continue;
        float4 y = make_float4(acc[r].x + bs4.x, acc[r].y + bs4.y,
                               acc[r].z + bs4.z, acc[r].w + bs4.w);
        st4(X1 + (size_t)gr * 128 + cg * 4, y);
        uint2 pk;
        pk.x = pack2(y.x, y.y);
        pk.y = pack2(y.z, y.w);
        *reinterpret_cast<uint2*>(X1_16 + (size_t)gr * 128 + cg * 4) = pk;
    }
}

// ---------------- L2 fused: Agg(X1_16) -> @W2 -> +b2/LN/ReLU -> +X1 -> X2 ----------------
// 512 thr, 32 nodes/block, G=16. LDS ~33.4KB -> 4 blocks/CU.

__global__ __launch_bounds__(512, 8) void k_l2_fused(
        const ushortT* __restrict__ t16, const int* __restrict__ csr,
        const int* __restrict__ rs, const int* __restrict__ re,
        const float* __restrict__ dinv,
        const float* __restrict__ W, const float* __restrict__ bias,
        const float* __restrict__ g, const float* __restrict__ be,
        const float* __restrict__ skip,
        float* __restrict__ out32, int n) {
    constexpr int NODES = 32, G = 16, KP = 136, KH = 32;
    __shared__ float Wl[KH][128];
    __shared__ float Xl[NODES][KP];

    const int tid = threadIdx.x;

    // ---- Phase A ----
    {
        const int grp = tid / G, sub = tid % G;
        const int node = blockIdx.x * NODES + grp;
        float a[8];
#pragma unroll
        for (int i = 0; i < 8; ++i) a[i] = 0.f;

        if (node < n) {
            const float di = dinv[node];
            const ushortT* base = t16 + sub * 8;
            const int p0 = rs[node], p1 = re[node];
            int p = p0;
            for (; p + 4 <= p1; p += 4) {
                int s0 = csr[p], s1 = csr[p + 1], s2 = csr[p + 2], s3 = csr[p + 3];
                float w0 = dinv[s0] * di, w1 = dinv[s1] * di, w2 = dinv[s2] * di, w3 = dinv[s3] * di;
                uint4 v0 = *reinterpret_cast<const uint4*>(base + (size_t)s0 * 128);
                uint4 v1 = *reinterpret_cast<const uint4*>(base + (size_t)s1 * 128);
                uint4 v2 = *reinterpret_cast<const uint4*>(base + (size_t)s2 * 128);
                uint4 v3 = *reinterpret_cast<const uint4*>(base + (size_t)s3 * 128);
                acc8(a, v0, w0); acc8(a, v1, w1); acc8(a, v2, w2); acc8(a, v3, w3);
            }
            for (; p < p1; ++p) {
                int s0 = csr[p];
                float w0 = dinv[s0] * di;
                uint4 v0 = *reinterpret_cast<const uint4*>(base + (size_t)s0 * 128);
                acc8(a, v0, w0);
            }
            uint4 v = *reinterpret_cast<const uint4*>(base + (size_t)node * 128);
            acc8(a, v, di * di);
        }
        st4(&Xl[grp][sub * 8], make_float4(a[0], a[1], a[2], a[3]));
        st4(&Xl[grp][sub * 8 + 4], make_float4(a[4], a[5], a[6], a[7]));
    }

    // ---- Phase B ----
    const int cg = tid & 31;
    const int rg = tid >> 5;   // 0..15, RPT=2
    const float4 bias4 = ld4(bias + cg * 4);
    float4 acc[2];
    acc[0] = bias4; acc[1] = bias4;

    for (int kh = 0; kh < 128; kh += KH) {
        __syncthreads();
        for (int i = tid; i < KH * 32; i += 512) {
            int kk = i >> 5, c = i & 31;
            st4(&Wl[kk][c * 4], ld4(W + (size_t)(kh + kk) * 128 + c * 4));
        }
        __syncthreads();
#pragma unroll 4
        for (int kk = 0; kk < KH; ++kk) {
            float4 w4 = ld4(&Wl[kk][cg * 4]);
#pragma unroll
            for (int r = 0; r < 2; ++r) {
                float xv = Xl[rg * 2 + r][kh + kk];
                acc[r].x = fmaf(xv, w4.x, acc[r].x);
                acc[r].y = fmaf(xv, w4.y, acc[r].y);
                acc[r].z = fmaf(xv, w4.z, acc[r].z);
                acc[r].w = fmaf(xv, w4.w, acc[r].w);
            }
        }
    }

    const float4 g4 = ld4(g + cg * 4);
    const float4 be4 = ld4(be + cg * 4);
#pragma unroll
    for (int r = 0; r < 2; ++r) {
        int gr = blockIdx.x * NODES + rg * 2 + r;
        if (gr >= n) continue;
        float4 a = acc[r];
        float sum = a.x + a.y + a.z + a.w;
#pragma unroll
        for (int m = 16; m > 0; m >>= 1) sum += __shfl_xor(sum, m, 32);
        const float mean = sum * (1.f / 128.f);
        float dx = a.x - mean, dy = a.y - mean, dz = a.z - mean, dw = a.w - mean;
        float sq = dx * dx + dy * dy + dz * dz + dw * dw;
#pragma unroll
        for (int m = 16; m > 0; m >>= 1) sq += __shfl_xor(sq, m, 32);
        const float rstd = rsqrtf(sq * (1.f / 128.f) + LN_EPS);
        float4 s4 = ld4(skip + (size_t)gr * 128 + cg * 4);
        float4 y;
        y.x = fmaxf(fmaf(dx * rstd, g4.x, be4.x), 0.f) + s4.x;
        y.y = fmaxf(fmaf(dy * rstd, g4.y, be4.y), 0.f) + s4.y;
        y.z = fmaxf(fmaf(dz * rstd, g4.z, be4.z), 0.f) + s4.z;
        y.w = fmaxf(fmaf(dw * rstd, g4.w, be4.w), 0.f) + s4.w;
        st4(out32 + (size_t)gr * 128 + cg * 4, y);
    }
}

// ---------------- L3 fused: Agg(hw3_16) + X1_16@Ws2 + b3 + bs2 -> out ----------------
// 512 thr, 64 nodes/block, G=8. LDS ~39.9KB -> 4 blocks/CU.

__global__ __launch_bounds__(512, 8) void k_l3_fused(
        const ushortT* __restrict__ hw16, const ushortT* __restrict__ x1_16,
        const int* __restrict__ csr, const int* __restrict__ rs, const int* __restrict__ re,
        const float* __restrict__ dinv,
        const float* __restrict__ Ws2, const float* __restrict__ bs2, const float* __restrict__ b3,
        float* __restrict__ out, int n) {
    constexpr int NODES = 64, G = 8;
    __shared__ float Xl[NODES][72];       // aggregated hw3 (f32, 64-wide)
    __shared__ ushortT Xown[NODES][136];  // own x1 row (bf16, 128-wide)
    __shared__ float Wl[16][64];

    const int tid = threadIdx.x;

    // ---- Phase A ----
    {
        const int grp = tid / G, sub = tid % G;
        const int node = blockIdx.x * NODES + grp;
        float a[8];
#pragma unroll
        for (int i = 0; i < 8; ++i) a[i] = 0.f;
        uint4 o0 = make_uint4(0u, 0u, 0u, 0u), o1 = o0;

        if (node < n) {
            const float di = dinv[node];
            const ushortT* base = hw16 + sub * 8;
            const int p0 = rs[node], p1 = re[node];
            int p = p0;
            for (; p + 4 <= p1; p += 4) {
                int s0 = csr[p], s1 = csr[p + 1], s2 = csr[p + 2], s3 = csr[p + 3];
                float w0 = dinv[s0] * di, w1 = dinv[s1] * di, w2 = dinv[s2] * di, w3 = dinv[s3] * di;
                uint4 v0 = *reinterpret_cast<const uint4*>(base + (size_t)s0 * 64);
                uint4 v1 = *reinterpret_cast<const uint4*>(base + (size_t)s1 * 64);
                uint4 v2 = *reinterpret_cast<const uint4*>(base + (size_t)s2 * 64);
                uint4 v3 = *reinterpret_cast<const uint4*>(base + (size_t)s3 * 64);
                acc8(a, v0, w0); acc8(a, v1, w1); acc8(a, v2, w2); acc8(a, v3, w3);
            }
            for (; p < p1; ++p) {
                int s0 = csr[p];
                float w0 = dinv[s0] * di;
                uint4 v0 = *reinterpret_cast<const uint4*>(base + (size_t)s0 * 64);
                acc8(a, v0, w0);
            }
            uint4 v = *reinterpret_cast<const uint4*>(base + (size_t)node * 64);
            acc8(a, v, di * di);
            const uint4* xr = reinterpret_cast<const uint4*>(x1_16 + (size_t)node * 128 + sub * 16);
            o0 = xr[0];
            o1 = xr[1];
        }
        st4(&Xl[grp][sub * 8], make_float4(a[0], a[1], a[2], a[3]));
        st4(&Xl[grp][sub * 8 + 4], make_float4(a[4], a[5], a[6], a[7]));
        *reinterpret_cast<uint4*>(&Xown[grp][sub * 16]) = o0;
        *reinterpret_cast<uint4*>(&Xown[grp][sub * 16 + 8]) = o1;
    }

    __syncthreads();

    // ---- Phase B: acc = agg + b3 + bs2 + Xown @ Ws2 ----
    const int cg = tid & 15;   // 16 col groups x 4
    const int rg = tid >> 4;   // 0..31, RPT=2
    const float4 b3_4 = ld4(b3 + cg * 4);
    const float4 bs2_4 = ld4(bs2 + cg * 4);
    float4 acc[2];
#pragma unroll
    for (int r = 0; r < 2; ++r) {
        float4 ag = ld4(&Xl[rg * 2 + r][cg * 4]);
        acc[r] = make_float4(ag.x + b3_4.x + bs2_4.x, ag.y + b3_4.y + bs2_4.y,
                             ag.z + b3_4.z + bs2_4.z, ag.w + b3_4.w + bs2_4.w);
    }

    for (int kh = 0; kh < 128; kh += 16) {
        __syncthreads();
        if (tid < 256) {
            int kk = tid >> 4, c = tid & 15;
            st4(&Wl[kk][c * 4], ld4(Ws2 + (size_t)(kh + kk) * 64 + c * 4));
        }
        __syncthreads();
#pragma unroll 4
        for (int kk = 0; kk < 16; kk += 2) {
            float4 wa = ld4(&Wl[kk][cg * 4]);
            float4 wb = ld4(&Wl[kk + 1][cg * 4]);
#pragma unroll
            for (int r = 0; r < 2; ++r) {
                unsigned xp = *reinterpret_cast<const unsigned*>(&Xown[rg * 2 + r][kh + kk]);
                float x0 = bf2f(xp & 0xffffu), x1 = bf2f(xp >> 16);
                acc[r].x = fmaf(x0, wa.x, acc[r].x); acc[r].y = fmaf(x0, wa.y, acc[r].y);
                acc[r].z = fmaf(x0, wa.z, acc[r].z); acc[r].w = fmaf(x0, wa.w, acc[r].w);
                acc[r].x = fmaf(x1, wb.x, acc[r].x); acc[r].y = fmaf(x1, wb.y, acc[r].y);
                acc[r].z = fmaf(x1, wb.z, acc[r].z); acc[r].w = fmaf(x1, wb.w, acc[r].w);
            }
        }
    }

#pragma unroll
    for (int r = 0; r < 2; ++r) {
        int gr = blockIdx.x * NODES + rg * 2 + r;
        if (gr < n) st4(out + (size_t)gr * 64 + cg * 4, acc[r]);
    }
}

// ---------------- small-K GEMM: out[N,64] = in[N,128] @ W (bf16 out) ----------------

__global__ __launch_bounds__(256) void gemm_hw3(const float* __restrict__ in, const float* __restrict__ W,
                                                ushortT* __restrict__ outp, int nrows) {
    constexpr int K = 128, M = 64, CG = 16, RPT = 2, ROWS = 32, KH = 32, KP = K + 4;

    __shared__ float Wl[KH][M];
    __shared__ float Xl[ROWS][KP];

    const int tid = threadIdx.x;
    const int cg = tid % CG;
    const int rg = tid / CG;

    for (int base = blockIdx.x * ROWS; base < nrows; base += gridDim.x * ROWS) {
        __syncthreads();
        for (int i = tid; i < ROWS * K / 4; i += 256) {
            int r = i / (K / 4), c = i % (K / 4);
            int gr = base + r;
            float4 v = make_float4(0.f, 0.f, 0.f, 0.f);
            if (gr < nrows) v = ld4(in + (size_t)gr * K + c * 4);
            st4(&Xl[r][c * 4], v);
        }

        float4 acc[RPT];
#pragma unroll
        for (int r = 0; r < RPT; ++r) acc[r] = make_float4(0.f, 0.f, 0.f, 0.f);

        for (int kh = 0; kh < K; kh += KH) {
            __syncthreads();
            for (int i = tid; i < KH * M / 4; i += 256) {
                int kk = i / (M / 4), c = i % (M / 4);
                st4(&Wl[kk][c * 4], ld4(W + (size_t)(kh + kk) * M + c * 4));
            }
            __syncthreads();
#pragma unroll 4
            for (int kk = 0; kk < KH; ++kk) {
                float4 w4 = ld4(&Wl[kk][cg * 4]);
#pragma unroll
                for (int r = 0; r < RPT; ++r) {
                    float xv = Xl[rg * RPT + r][kh + kk];
                    acc[r].x = fmaf(xv, w4.x, acc[r].x);
                    acc[r].y = fmaf(xv, w4.y, acc[r].y);
                    acc[r].z = fmaf(xv, w4.z, acc[r].z);
                    acc[r].w = fmaf(xv, w4.w, acc[r].w);
                }
            }
        }
#pragma unroll
        for (int r = 0; r < RPT; ++r) {
            int gr = base + rg * RPT + r;
            if (gr < nrows) {
                uint2 pk;
                pk.x = pack2(acc[r].x, acc[r].y);
                pk.y = pack2(acc[r].z, acc[r].w);
                *reinterpret_cast<uint2*>(outp + (size_t)gr * M + cg * 4) = pk;
            }
        }
    }
}

// ---------------- launch ----------------

extern "C" void kernel_launch(void* const* d_in, const int* in_sizes, int n_in,
                              void* d_out, int out_size, void* d_ws, size_t ws_size,
                              hipStream_t stream) {
    const float* x   = (const float*)d_in[0];
    const int* eidx  = (const int*)d_in[1];
    const float* W1  = (const float*)d_in[2];
    const float* b1  = (const float*)d_in[3];
    const float* W2  = (const float*)d_in[4];
    const float* b2  = (const float*)d_in[5];
    const float* W3  = (const float*)d_in[6];
    const float* b3  = (const float*)d_in[7];
    const float* g1  = (const float*)d_in[8];
    const float* be1 = (const float*)d_in[9];
    const float* g2  = (const float*)d_in[10];
    const float* be2 = (const float*)d_in[11];
    const float* Ws1 = (const float*)d_in[12];
    const float* bs1 = (const float*)d_in[13];
    const float* Ws2 = (const float*)d_in[14];
    const float* bs2 = (const float*)d_in[15];
    float* out = (float*)d_out;

    const int N = in_sizes[0] / 64;
    const int E = in_sizes[1] / 2;
    const int* esrc = eidx;
    const int* edst = eidx + E;

    char* p = (char*)d_ws;
    auto alloc = [&](size_t bytes) -> char* {
        char* q = p;
        p += (bytes + 255) & ~(size_t)255;
        return q;
    };
    float* X1       = (float*)alloc((size_t)N * 128 * 4);
    float* X2       = (float*)alloc((size_t)N * 128 * 4);
    ushortT* x16    = (ushortT*)alloc((size_t)N * 64 * 2);
    ushortT* X1_16  = (ushortT*)alloc((size_t)N * 128 * 2);
    ushortT* HW3_16 = (ushortT*)alloc((size_t)N * 64 * 2);
    int* csr        = (int*)alloc((size_t)E * 4);
    int* counts     = (int*)alloc((size_t)N * 4);
    int* offsets    = (int*)alloc((size_t)N * 4);
    int* cursor     = (int*)alloc((size_t)N * 4);
    float* dinv     = (float*)alloc((size_t)N * 4);
    const int NB = (N + 511) / 512;
    int* bsum       = (int*)alloc((size_t)NB * 4);

    const int gN256 = (N + 255) / 256;
    const int gE256 = (E + 255) / 256;

    // ---- CSR build ----
    k_zero_i32<<<gN256, 256, 0, stream>>>(counts, N);
    k_count<<<gE256, 256, 0, stream>>>(edst, counts, E);
    k_dinv<<<gN256, 256, 0, stream>>>(counts, dinv, N);
    k_scan1<<<NB, 512, 0, stream>>>(counts, bsum, N);
    k_scan2<<<1, 512, 0, stream>>>(bsum, NB);
    k_scan3<<<NB, 512, 0, stream>>>(counts, bsum, offsets, cursor, N);
    k_fill<<<gE256, 256, 0, stream>>>(esrc, edst, cursor, csr, E);
    // cursor[i] = row end

    // ---- layer 1 (fused conv+LN+relu+skip1) ----
    k_cvt_bf16<<<(N * 16 + 255) / 256, 256, 0, stream>>>(x, x16, N * 16);
    k_l1_fused<<<(N + 63) / 64, 512, 0, stream>>>(x16, csr, offsets, cursor, dinv,
                                                  W1, b1, g1, be1, Ws1, bs1,
                                                  X1, X1_16, N);

    // ---- layer 2 ----
    k_l2_fused<<<(N + 31) / 32, 512, 0, stream>>>(X1_16, csr, offsets, cursor, dinv,
                                                  W2, b2, g2, be2, X1, X2, N);

    // ---- layer 3 (hw3 GEMM, then fused agg+skip3) ----
    gemm_hw3<<<(N + 31) / 32, 256, 0, stream>>>(X2, W3, HW3_16, N);
    k_l3_fused<<<(N + 63) / 64, 512, 0, stream>>>(HW3_16, X1_16, csr, offsets, cursor,
                                                  dinv, Ws2, bs2, b3, out, N);
}